// Round 2
// 6111.292 us; speedup vs baseline: 1.0109x; 1.0109x over previous
//
#include <hip/hip_runtime.h>

#define Tt  128
#define HID 512

// Generic C[m,n] = sum_k A[m,k]*Bw[r(n),k] (+bias[r(n)]) (+C0[m/c0div, n])
// nperm: physical col n <-> logical weight row r(n) = (n&3)*512 + (n>>2),
// i.e. output stored gate-interleaved [.., j, 4gates] while writes stay coalesced.
__global__ __launch_bounds__(256)
void gemm_bt(const float* __restrict__ A, const float* __restrict__ Bw,
             const float* __restrict__ bias, const float* __restrict__ C0,
             float* __restrict__ C,
             int M, int N, int K, int lda, int ldb, int ldc, int ldc0,
             int c0div, int nperm)
{
    __shared__ float As[16][68];
    __shared__ float Bs[16][68];
    const int n0 = blockIdx.x * 64;
    const int m0 = blockIdx.y * 64;
    const int tid = threadIdx.x;
    const int tx = tid & 15, ty = tid >> 4;
    float acc[4][4];
#pragma unroll
    for (int i = 0; i < 4; i++)
#pragma unroll
        for (int j = 0; j < 4; j++) acc[i][j] = 0.f;

    for (int k0 = 0; k0 < K; k0 += 16) {
#pragma unroll
        for (int i = 0; i < 4; i++) {
            int e = tid + i * 256;
            int m = e >> 4, k = e & 15;
            As[k][m] = A[(size_t)(m0 + m) * lda + (k0 + k)];
        }
#pragma unroll
        for (int i = 0; i < 4; i++) {
            int e = tid + i * 256;
            int n = e >> 4, k = e & 15;
            int gn = n0 + n;
            int gr = nperm ? ((gn & 3) * HID + (gn >> 2)) : gn;
            Bs[k][n] = (gn < N) ? Bw[(size_t)gr * ldb + (k0 + k)] : 0.f;
        }
        __syncthreads();
#pragma unroll
        for (int kk = 0; kk < 16; kk++) {
            float4 av = *(const float4*)&As[kk][ty * 4];
            float4 bv = *(const float4*)&Bs[kk][tx * 4];
            float a[4] = {av.x, av.y, av.z, av.w};
            float b[4] = {bv.x, bv.y, bv.z, bv.w};
#pragma unroll
            for (int i = 0; i < 4; i++)
#pragma unroll
                for (int j = 0; j < 4; j++)
                    acc[i][j] += a[i] * b[j];
        }
        __syncthreads();
    }
#pragma unroll
    for (int i = 0; i < 4; i++) {
        int m = m0 + ty * 4 + i;
        const float* c0row = C0 ? (C0 + (size_t)(m / c0div) * ldc0) : nullptr;
#pragma unroll
        for (int j = 0; j < 4; j++) {
            int n = n0 + tx * 4 + j;
            if (n < N) {
                float v = acc[i][j];
                if (bias)  v += bias[nperm ? ((n & 3) * HID + (n >> 2)) : n];
                if (c0row) v += c0row[n];
                C[(size_t)m * ldc + n] = v;
            }
        }
    }
}

// Weight-stationary persistent LSTM recurrence.
// 256 blocks x 512 threads (1 block/CU, 8 waves). bt = blockIdx&7 (32 b rows),
// jt = blockIdx>>3 (16 j cols, all 4 gates -> 64 W rows per block).
// W_hh slice in VGPRs: thread (w, l) holds rows {j0+w*2+jj, gates 0..3} x
// k in [kc*16, kc*16+16) -> 8 rows x 4 float4 = 128 VGPR, loaded once.
// h exchanged through global in a TRANSPOSED layout: float4 index
// b*128 + kk4*32 + kc  (k = kc*16 + kk4*4 + e), staged to LDS by a straight
// register copy, so inner-loop ds_read_b128 are lane-contiguous
// (conflict-free). 32-way k-split resolved by a 5-step shfl_xor
// reduce-scatter: lane kc ends with gates {2gH,2gH+1} of
// (b = ot*16+gH*8+ip, j = j0+w*2+jjp); one more shfl_xor(1) pairs up the
// other two gates -> every lane does the pointwise for exactly one (b,j).
// Sync: per-bt flag counters (agent-scope release/acquire), 3 barriers/step.
__global__ __launch_bounds__(512, 2)
void lstm_seq(const float* __restrict__ gin, const float* __restrict__ Whh,
              float* __restrict__ hA, float* __restrict__ hB,
              float* __restrict__ hiddens, unsigned int* __restrict__ flags)
{
    __shared__ float4 Hs[4096];        // 64 KB: [b_local 0..31][kk4 0..3][kc 0..31]
    const int tid = threadIdx.x;
    const int l   = tid & 63;
    const int w   = tid >> 6;          // 0..7 -> j pair group (wave index)
    const int bt  = blockIdx.x & 7;
    const int jt  = blockIdx.x >> 3;   // 0..31
    const int b0  = bt * 32;
    const int j0  = jt * 16;
    const int ot  = l >> 5;            // b half (16 rows)
    const int kc  = l & 31;            // k chunk [kc*16, kc*16+16)

    // one-time W_hh load into registers (row = jj*4 + g convention)
    float4 Wr[8][4];
#pragma unroll
    for (int r = 0; r < 8; ++r) {
        int jj = r >> 2, g = r & 3;
        const float* src = Whh + (size_t)(g * HID + j0 + w * 2 + jj) * HID + kc * 16;
#pragma unroll
        for (int q = 0; q < 4; ++q) Wr[r][q] = *(const float4*)(src + q * 4);
    }

    // pointwise task of this lane (fixed across t): set by reduce-scatter bits
    const int ip  = kc >> 2;           // lane bits k4k3k2 = i
    const int jjp = (kc >> 1) & 1;     // k1 = jj
    const int gH  = kc & 1;            // k0 = gate-pair; also selects b half-of-8
    const int bp  = b0 + ot * 16 + gH * 8 + ip;   // global b
    const int jp  = j0 + w * 2 + jjp;             // global j
    // transposed h position (float index) for (bp, jp): k == jp
    const size_t hpos = ((size_t)bp * 128 + ((jp >> 2) & 3) * 32 + (jp >> 4)) * 4 + (jp & 3);

    float cr = 0.f;

    for (int t = 0; t < Tt; ++t) {
        // prefetch the 4 gate inputs (gin is gate-interleaved [b][t][j][4])
        float4 gv = *(const float4*)(gin + ((size_t)bp * Tt + t) * 2048 + jp * 4);

        float rA0 = 0.f, rA1 = 0.f, rB0 = 0.f, rB1 = 0.f;
        if (t > 0) {
            if (tid == 0) {
                while (__hip_atomic_load(&flags[bt], __ATOMIC_ACQUIRE,
                                         __HIP_MEMORY_SCOPE_AGENT) < 32u * (unsigned)t)
                    __builtin_amdgcn_s_sleep(1);
            }
            __syncthreads();
            // stage 32 b x 512 h (64 KB) -> LDS: straight register-staged copy
            // of the transposed layout (coalesced global, conflict-free LDS)
            {
                const float4* hin4 =
                    (const float4*)(((t - 1) & 1) ? hB : hA) + (size_t)b0 * 128;
                float4 tmp[8];
#pragma unroll
                for (int q = 0; q < 8; ++q)
                    tmp[q] = hin4[(q * 8 + w) * 64 + l];
#pragma unroll
                for (int q = 0; q < 8; ++q)
                    Hs[(q * 8 + w) * 64 + l] = tmp[q];
            }
            __syncthreads();

#pragma unroll
            for (int hb = 0; hb < 2; ++hb) {      // two 8-b halves (register pressure)
                float P[64];                      // [i 0..7][r 0..7], r = jj*4+g
#pragma unroll
                for (int v = 0; v < 64; ++v) P[v] = 0.f;
#pragma unroll
                for (int i = 0; i < 8; ++i) {
                    const float4* hp = &Hs[(ot * 16 + hb * 8 + i) * 128 + kc];
                    float4 h0 = hp[0], h1 = hp[32], h2 = hp[64], h3 = hp[96];
#pragma unroll
                    for (int r = 0; r < 8; ++r) {
                        P[i * 8 + r] +=
                            Wr[r][0].x * h0.x + Wr[r][0].y * h0.y + Wr[r][0].z * h0.z + Wr[r][0].w * h0.w +
                            Wr[r][1].x * h1.x + Wr[r][1].y * h1.y + Wr[r][1].z * h1.z + Wr[r][1].w * h1.w +
                            Wr[r][2].x * h2.x + Wr[r][2].y * h2.y + Wr[r][2].z * h2.z + Wr[r][2].w * h2.w +
                            Wr[r][3].x * h3.x + Wr[r][3].y * h3.y + Wr[r][3].z * h3.z + Wr[r][3].w * h3.w;
                    }
                }
                // reduce-scatter 64 values -> 2 across the 32 kc lanes.
                // step with mask 2^s pairs lane-bit s with the current top
                // value-bit; hi lane keeps the high half. Remaining bit = g0.
#define RS_STEP(MASK, CNT)                                              \
                {                                                       \
                    const int Hh = (CNT) / 2;                           \
                    const bool hi = (l & (MASK)) != 0;                  \
                    _Pragma("unroll")                                   \
                    for (int x = 0; x < Hh; ++x) {                      \
                        float a = P[x], b2 = P[Hh + x];                 \
                        float keep = hi ? b2 : a;                       \
                        float send = hi ? a : b2;                       \
                        P[x] = keep + __shfl_xor(send, (MASK), 64);     \
                    }                                                   \
                }
                RS_STEP(16, 64)
                RS_STEP(8, 32)
                RS_STEP(4, 16)
                RS_STEP(2, 8)
                RS_STEP(1, 4)
#undef RS_STEP
                if (hb == 0) { rA0 = P[0]; rA1 = P[1]; }
                else         { rB0 = P[0]; rB1 = P[1]; }
            }
        }
        // lane's task uses half hb == gH; swap the other half's pair with kc^1,
        // which holds the complementary gate pair for the same (b, j).
        float own0 = gH ? rB0 : rA0;
        float own1 = gH ? rB1 : rA1;
        float snd0 = gH ? rA0 : rB0;
        float snd1 = gH ? rA1 : rB1;
        float oth0 = __shfl_xor(snd0, 1, 64);
        float oth1 = __shfl_xor(snd1, 1, 64);
        float gi = (gH ? oth0 : own0) + gv.x;
        float gf = (gH ? oth1 : own1) + gv.y;
        float gg = (gH ? own0 : oth0) + gv.z;
        float go = (gH ? own1 : oth1) + gv.w;

        float si = 1.f / (1.f + __expf(-gi));
        float sf = 1.f / (1.f + __expf(-gf));
        float so = 1.f / (1.f + __expf(-go));
        float tg = 1.f - 2.f / (1.f + __expf(2.f * gg));
        float cv = sf * cr + si * tg;
        cr = cv;
        float th = 1.f - 2.f / (1.f + __expf(2.f * cv));
        float hv = so * th;

        float* hw = (t & 1) ? hB : hA;
        hw[hpos] = hv;                                        // transposed exchange buf
        hiddens[((size_t)bp * Tt + t) * HID + jp] = hv;       // standard layout for GEMM
        __syncthreads();   // all waves drain reads+stores (vmcnt0 at barrier)
        if (tid == 0) {
            __threadfence();
            __hip_atomic_fetch_add(&flags[bt], 1u, __ATOMIC_RELEASE,
                                   __HIP_MEMORY_SCOPE_AGENT);
        }
    }
}

extern "C" void kernel_launch(void* const* d_in, const int* in_sizes, int n_in,
                              void* d_out, int out_size, void* d_ws, size_t ws_size,
                              hipStream_t stream)
{
    const float* images = (const float*)d_in[0];
    const float* caps   = (const float*)d_in[1];
    const float* W_fc   = (const float*)d_in[2];
    const float* b_fc   = (const float*)d_in[3];
    const float* W_att  = (const float*)d_in[4];
    const float* b_att  = (const float*)d_in[5];
    const float* W_ih   = (const float*)d_in[6];
    const float* b_ih   = (const float*)d_in[7];
    const float* W_hh   = (const float*)d_in[8];
    const float* b_hh   = (const float*)d_in[9];
    const float* W_out  = (const float*)d_in[10];
    const float* b_out  = (const float*)d_in[11];
    float* out = (float*)d_out;

    float* ws       = (float*)d_ws;
    float* feats    = ws;                  // 256*256
    float* att_base = feats + 65536;       // 256*256
    float* gin_base = att_base + 65536;    // 256*2048 (gate-interleaved)
    float* hA       = gin_base + 524288;   // 256*512 (transposed layout)
    float* hB       = hA + 131072;
    float* ctx_all  = hB + 131072;         // 32768*256
    float* hiddens  = ctx_all + 8388608;   // 32768*512
    float* gin_all  = hiddens + 16777216;  // 32768*2048 (gate-interleaved)
    unsigned int* flags = (unsigned int*)(gin_all + 67108864);  // 8 counters

    hipMemsetAsync(flags, 0, 8 * sizeof(unsigned int), stream);

    // 1. feats = images @ W_fc^T + b_fc            [256,256]
    gemm_bt<<<dim3(4, 4), 256, 0, stream>>>(images, W_fc, b_fc, nullptr, feats,
        256, 256, 2048, 2048, 2048, 256, 0, 1, 0);
    // 2. att_base = feats @ W_att[:, :256]^T + b_att   [256,256]
    gemm_bt<<<dim3(4, 4), 256, 0, stream>>>(feats, W_att, b_att, nullptr, att_base,
        256, 256, 256, 256, 768, 256, 0, 1, 0);
    // 3. gin_base = feats @ W_ih[:, :256]^T + b_ih     [256,2048] gate-interleaved
    gemm_bt<<<dim3(32, 4), 256, 0, stream>>>(feats, W_ih, b_ih, nullptr, gin_base,
        256, 2048, 256, 256, 512, 2048, 0, 1, 1);
    // 4. ctx_all = caps @ W_att[:, 256:]^T + att_base  [32768,256]
    gemm_bt<<<dim3(4, 512), 256, 0, stream>>>(caps, W_att + 256, nullptr, att_base, ctx_all,
        32768, 256, 512, 512, 768, 256, 256, Tt, 0);
    // 5. gin_all = ctx_all @ W_ih[:, 256:]^T + gin_base + b_hh   [32768,2048] interleaved
    gemm_bt<<<dim3(32, 512), 256, 0, stream>>>(ctx_all, W_ih + 256, b_hh, gin_base, gin_all,
        32768, 2048, 256, 256, 512, 2048, 2048, Tt, 1);

    // 6. recurrence: weight-stationary persistent kernel, 256 x 512, flag-synced
    {
        void* args[] = { (void*)&gin_all, (void*)&W_hh, (void*)&hA, (void*)&hB,
                         (void*)&hiddens, (void*)&flags };
        hipLaunchCooperativeKernel((void*)lstm_seq, dim3(256), dim3(512),
                                   args, 0, stream);
    }

    // 7. out = hiddens @ W_out^T + b_out   [32768,1004]
    gemm_bt<<<dim3(16, 512), 256, 0, stream>>>(hiddens, W_out, b_out, nullptr, out,
        32768, 1004, 512, 512, 512, 1004, 0, 1, 0);
}